// Round 5
// baseline (791.221 us; speedup 1.0000x reference)
//
#include <hip/hip_runtime.h>

#define NB 1024
#define NT 256
#define IND 10
#define HID 64
#define WPJ 404   // packed weight floats per output column j

// ---------------------------------------------------------------------------
// Weight repack (unchanged layout):
//   0..119   : Ws  (W1[11+q]+W1[132+q]) in payload order [A(10),B(10),C(100)]
//   120..239 : Wb  (W1[253+q])   gated by rel0
//   240..359 : Wc  (W1[374+q])   gated by rel1
//   360..369 : wdA, 370: wdB0, 371..375: wdC   (rel2-gated 17-term)
//   376..385 : wrel (sig1), 386..395: wf (features)
//   396..399 : tt coefs (ws,wb,wc,wd), 400: w_one, 401: b1[j], 402..403 pad
// payload order: q=1+c (A), q=11*(i+1) (B), q=11*(i+1)+1+c (C)
// ---------------------------------------------------------------------------
__device__ __forceinline__ int qmap(int kk) {
    if (kk < 10) return 1 + kk;
    if (kk < 20) return 11 * (kk - 10 + 1);
    int i = (kk - 20) / 10, c = (kk - 20) % 10;
    return 11 * (i + 1) + 1 + c;
}

__global__ void pack_kernel(const float* __restrict__ W1, const float* __restrict__ b1,
                            float* __restrict__ Wr) {
    int idx = blockIdx.x * 256 + threadIdx.x;
    if (idx >= 64 * WPJ) return;
    int j = idx / WPJ, k = idx % WPJ;
    float v = 0.f;
    if (k < 120)       { int q = qmap(k);       v = W1[(11+q)*64+j] + W1[(132+q)*64+j]; }
    else if (k < 240)  { int q = qmap(k - 120); v = W1[(253+q)*64+j]; }
    else if (k < 360)  { int q = qmap(k - 240); v = W1[(374+q)*64+j]; }
    else if (k < 370)  { v = W1[(495 + 1 + (k-360))*64 + j]; }
    else if (k == 370) { v = W1[(495 + 11)*64 + j]; }
    else if (k < 376)  { v = W1[(495 + 12 + (k-371))*64 + j]; }
    else if (k < 386)  { v = W1[(1 + (k-376))*64 + j]; }
    else if (k < 396)  { v = W1[(512 + (k-386))*64 + j]; }
    else if (k == 396) { v = W1[11*64+j] + W1[132*64+j]; }
    else if (k == 397) { v = W1[253*64+j]; }
    else if (k == 398) { v = W1[374*64+j]; }
    else if (k == 399) { v = W1[495*64+j]; }
    else if (k == 400) { v = W1[0*64+j]; }
    else if (k == 401) { v = b1[j]; }
    Wr[idx] = v;
}

__device__ __forceinline__ float4 shfl_up4(float4 v, int d) {
    float4 r;
    r.x = __shfl_up(v.x, d, 64);
    r.y = __shfl_up(v.y, d, 64);
    r.z = __shfl_up(v.z, d, 64);
    r.w = __shfl_up(v.w, d, 64);
    return r;
}

// The 120-float prefix payload lives in 30 NAMED float4s (P0..P29) — no
// alloca, so it cannot be demoted to scratch (round-2/3's P[120] array was:
// SROA fails pre-unroll, backend promote-alloca caps <480B -> 900 MB scratch).
#define P_EACH(X) X(0) X(1) X(2) X(3) X(4) X(5) X(6) X(7) X(8) X(9) \
    X(10) X(11) X(12) X(13) X(14) X(15) X(16) X(17) X(18) X(19) \
    X(20) X(21) X(22) X(23) X(24) X(25) X(26) X(27) X(28) X(29)

// payload element k: k<10 -> tf*inc[k]; k<20 -> rel[k-10]; else rel[i]*inc[c]
#define PAY(k) ((k) < 10 ? tf * inc[(k)] : \
               ((k) < 20 ? rel[(k) - 10] : \
                rel[((k) - 20) / 10] * inc[((k) - 20) % 10]))

__global__ __launch_bounds__(256, 1) void presig_kernel(
    const float* __restrict__ features, const float* __restrict__ Wr,
    float* __restrict__ pre1) {
    const int b = blockIdx.x;
    const int t = threadIdx.x;
    const int lane = t & 63;
    const int w = t >> 6;

    __shared__ __align__(16) float sF[NT * IND];
    __shared__ __align__(16) float sWS[3][120];

    {
        const float4* src = (const float4*)(features + b * (NT * IND));
        float4* dst = (float4*)sF;
        for (int idx = t; idx < NT * IND / 4; idx += 256) dst[idx] = src[idx];
    }
    __syncthreads();

    float F[10], rel[10], inc[10];
#pragma unroll
    for (int f = 0; f < 10; ++f) F[f] = sF[t * 10 + f];
#pragma unroll
    for (int f = 0; f < 10; ++f) rel[f] = F[f] - sF[f];
#pragma unroll
    for (int f = 0; f < 10; ++f)
        inc[f] = (t < 255) ? (sF[(t + 1) * 10 + f] - F[f]) : 0.f;

    float tf = (float)t;

#define DECLP(q) float4 P##q;
    P_EACH(DECLP)
#undef DECLP
#define INITP(q) P##q = make_float4(PAY(4*(q)+0), PAY(4*(q)+1), PAY(4*(q)+2), PAY(4*(q)+3));
    P_EACH(INITP)
#undef INITP

    // wave-level inclusive scan (Hillis-Steele over 64 lanes)
#define SCANP(q) { float4 v = shfl_up4(P##q, d); if (ok) { \
    P##q.x += v.x; P##q.y += v.y; P##q.z += v.z; P##q.w += v.w; } }
    for (int d = 1; d < 64; d <<= 1) {
        bool ok = lane >= d;
        P_EACH(SCANP)
    }
#undef SCANP

    // cross-wave fixup
    if (lane == 63 && w < 3) {
        float4* dst = (float4*)sWS[w];
#define SAVEP(q) dst[(q)] = P##q;
        P_EACH(SAVEP)
#undef SAVEP
    }
    __syncthreads();
#define ADDW(q) { float4 v = sws[(q)]; P##q.x += v.x; P##q.y += v.y; P##q.z += v.z; P##q.w += v.w; }
    if (w >= 1) { const float4* sws = (const float4*)sWS[0]; P_EACH(ADDW) }
    if (w >= 2) { const float4* sws = (const float4*)sWS[1]; P_EACH(ADDW) }
    if (w == 3) { const float4* sws = (const float4*)sWS[2]; P_EACH(ADDW) }
#undef ADDW

    // inclusive -> exclusive: subtract own payload
#define EXCL(q) { P##q.x -= PAY(4*(q)+0); P##q.y -= PAY(4*(q)+1); \
                  P##q.z -= PAY(4*(q)+2); P##q.w -= PAY(4*(q)+3); }
    P_EACH(EXCL)
#undef EXCL

    // fold inv_k into A,B sections (elements 0..19 = P0..P4)
    float inv_k = (t > 0) ? 1.f / tf : 0.f;
    float tt = 0.5f * (tf - 1.f) * inv_k;
    P0.x *= inv_k; P0.y *= inv_k; P0.z *= inv_k; P0.w *= inv_k;
    P1.x *= inv_k; P1.y *= inv_k; P1.z *= inv_k; P1.w *= inv_k;
    P2.x *= inv_k; P2.y *= inv_k; P2.z *= inv_k; P2.w *= inv_k;
    P3.x *= inv_k; P3.y *= inv_k; P3.z *= inv_k; P3.w *= inv_k;
    P4.x *= inv_k; P4.y *= inv_k; P4.z *= inv_k; P4.w *= inv_k;

    float w_one_gate = (t > 0) ? 1.f : 0.f;
    float* outp = pre1 + b * (NT * HID) + t * HID;

    const float* wj = Wr;   // wave-uniform -> scalar loads
    for (int j = 0; j < 64; ++j, wj += WPJ) {
        float4 pa = make_float4(0.f, 0.f, 0.f, 0.f);
        float4 pb = make_float4(0.f, 0.f, 0.f, 0.f);
        float4 pc = make_float4(0.f, 0.f, 0.f, 0.f);
#define DOTQ(q) { \
        float4 a4 = *(const float4*)(wj + 4*(q)); \
        float4 b4 = *(const float4*)(wj + 120 + 4*(q)); \
        float4 c4 = *(const float4*)(wj + 240 + 4*(q)); \
        pa.x = fmaf(P##q.x, a4.x, pa.x); pa.y = fmaf(P##q.y, a4.y, pa.y); \
        pa.z = fmaf(P##q.z, a4.z, pa.z); pa.w = fmaf(P##q.w, a4.w, pa.w); \
        pb.x = fmaf(P##q.x, b4.x, pb.x); pb.y = fmaf(P##q.y, b4.y, pb.y); \
        pb.z = fmaf(P##q.z, b4.z, pb.z); pb.w = fmaf(P##q.w, b4.w, pb.w); \
        pc.x = fmaf(P##q.x, c4.x, pc.x); pc.y = fmaf(P##q.y, c4.y, pc.y); \
        pc.z = fmaf(P##q.z, c4.z, pc.z); pc.w = fmaf(P##q.w, c4.w, pc.w); }
        P_EACH(DOTQ)
#undef DOTQ
        // rel2-gated 17-term: needs P[0..9] (P0,P1,P2.xy), P[10]=P2.z, P[20..24]=P5,P6.x
        float dd = tt * wj[399];
        dd = fmaf(P0.x, wj[360], dd); dd = fmaf(P0.y, wj[361], dd);
        dd = fmaf(P0.z, wj[362], dd); dd = fmaf(P0.w, wj[363], dd);
        dd = fmaf(P1.x, wj[364], dd); dd = fmaf(P1.y, wj[365], dd);
        dd = fmaf(P1.z, wj[366], dd); dd = fmaf(P1.w, wj[367], dd);
        dd = fmaf(P2.x, wj[368], dd); dd = fmaf(P2.y, wj[369], dd);
        dd = fmaf(P2.z, wj[370], dd);
        dd = fmaf(P5.x, wj[371], dd); dd = fmaf(P5.y, wj[372], dd);
        dd = fmaf(P5.z, wj[373], dd); dd = fmaf(P5.w, wj[374], dd);
        dd = fmaf(P6.x, wj[375], dd);

        float ds = (pa.x + pa.y) + (pa.z + pa.w) + tt * wj[396];
        float db = (pb.x + pb.y) + (pb.z + pb.w) + tt * wj[397];
        float dc = (pc.x + pc.y) + (pc.z + pc.w) + tt * wj[398];
        float pre = ds + rel[0] * db + rel[1] * dc + rel[2] * dd;
        pre = fmaf(w_one_gate, wj[400], pre);
#pragma unroll
        for (int c = 0; c < 10; ++c) pre = fmaf(rel[c], wj[376 + c], pre);
#pragma unroll
        for (int c = 0; c < 10; ++c) pre = fmaf(F[c], wj[386 + c], pre);
        pre += wj[401];
        outp[j] = pre;
    }
}

// ---------------------------------------------------------------------------
// Kernel B: per-batch sequential scan, one wave per batch.
//  - W2 column in 16 NAMED float4s (no scratch possible)
//  - 8-deep named prefetch ring for pre1 (hides L3 latency)
//  - LDS broadcast for h1 (single-wave barrier is cheap)
//  - DPP wave-sum (6 VALU ops, ctrl/rmask as TEMPLATE constants)
//  - coalesced output: buffer 64 deltas, one coalesced store per 64 steps
// ---------------------------------------------------------------------------
template <int CTRL, int RMASK>
__device__ __forceinline__ float dpp_add(float x) {
    int v = __builtin_amdgcn_update_dpp(0, __float_as_int(x), CTRL, RMASK, 0xf, false);
    return x + __int_as_float(v);
}

#define W2_EACH(X) X(0) X(1) X(2) X(3) X(4) X(5) X(6) X(7) \
    X(8) X(9) X(10) X(11) X(12) X(13) X(14) X(15)

__global__ __launch_bounds__(64, 1) void scan_kernel(
    const float* __restrict__ pre1, const float* __restrict__ W1,
    const float* __restrict__ W2, const float* __restrict__ b2,
    const float* __restrict__ W3, const float* __restrict__ b3,
    float* __restrict__ out) {
    const int b = blockIdx.x;
    const int j = threadIdx.x;

    __shared__ __align__(16) float sH[64];

#define DECLW(q) float4 w2_##q = make_float4( \
        W2[(4*(q)+0)*64 + j], W2[(4*(q)+1)*64 + j], \
        W2[(4*(q)+2)*64 + j], W2[(4*(q)+3)*64 + j]);
    W2_EACH(DECLW)
#undef DECLW
    float w1l = W1[522 * 64 + j];
    float b2j = b2[j], w3j = W3[j], b3v = b3[0];

    const float* pb_ = pre1 + b * (NT * HID);
    float delta = 0.f;
    float outbuf = 0.f;

#define GEMVQ(q) { float4 h4 = *(const float4*)&sH[4*(q)]; \
        a0 = fmaf(h4.x, w2_##q.x, a0); a1 = fmaf(h4.y, w2_##q.y, a1); \
        a2 = fmaf(h4.z, w2_##q.z, a2); a3 = fmaf(h4.w, w2_##q.w, a3); }

#define SCAN_STEP(pv, mm) { \
        float h1 = fmaxf(fmaf(delta, w1l, (pv)), 0.f); \
        sH[j] = h1; \
        __syncthreads(); \
        float a0 = 0.f, a1 = 0.f, a2 = 0.f, a3 = 0.f; \
        W2_EACH(GEMVQ) \
        __syncthreads(); \
        float h2 = fmaxf((a0 + a1) + (a2 + a3) + b2j, 0.f); \
        float qv = h2 * w3j; \
        qv = dpp_add<0x111, 0xf>(qv); \
        qv = dpp_add<0x112, 0xf>(qv); \
        qv = dpp_add<0x114, 0xf>(qv); \
        qv = dpp_add<0x118, 0xf>(qv); \
        qv = dpp_add<0x142, 0xa>(qv); \
        qv = dpp_add<0x143, 0xc>(qv); \
        float tot = __int_as_float(__builtin_amdgcn_readlane(__float_as_int(qv), 63)); \
        delta = tot + b3v; \
        if (j == ((mm) & 63)) outbuf = delta; \
        if (((mm) & 63) == 63) out[b * NT + ((mm) & ~63) + j] = outbuf; }

    // prefetch ring: 8 named registers, loads issue one group (8 steps) ahead
    float r0 = pb_[0 * 64 + j], r1 = pb_[1 * 64 + j], r2 = pb_[2 * 64 + j],
          r3 = pb_[3 * 64 + j], r4 = pb_[4 * 64 + j], r5 = pb_[5 * 64 + j],
          r6 = pb_[6 * 64 + j], r7 = pb_[7 * 64 + j];
    for (int g = 0; g < NT; g += 8) {
        int nb = g + 8;
        float n0 = pb_[min(nb + 0, NT - 1) * 64 + j];
        float n1 = pb_[min(nb + 1, NT - 1) * 64 + j];
        float n2 = pb_[min(nb + 2, NT - 1) * 64 + j];
        float n3 = pb_[min(nb + 3, NT - 1) * 64 + j];
        float n4 = pb_[min(nb + 4, NT - 1) * 64 + j];
        float n5 = pb_[min(nb + 5, NT - 1) * 64 + j];
        float n6 = pb_[min(nb + 6, NT - 1) * 64 + j];
        float n7 = pb_[min(nb + 7, NT - 1) * 64 + j];
        SCAN_STEP(r0, g + 0)
        SCAN_STEP(r1, g + 1)
        SCAN_STEP(r2, g + 2)
        SCAN_STEP(r3, g + 3)
        SCAN_STEP(r4, g + 4)
        SCAN_STEP(r5, g + 5)
        SCAN_STEP(r6, g + 6)
        SCAN_STEP(r7, g + 7)
        r0 = n0; r1 = n1; r2 = n2; r3 = n3; r4 = n4; r5 = n5; r6 = n6; r7 = n7;
    }
#undef SCAN_STEP
#undef GEMVQ
}

// ---------------------------------------------------------------------------
// Fallback (round-1 fused kernel) if workspace is too small for pre1.
// ---------------------------------------------------------------------------
__global__ __launch_bounds__(256) void logsig_hedge_fallback(
    const float* __restrict__ features, const float* __restrict__ W1,
    const float* __restrict__ b1, const float* __restrict__ W2,
    const float* __restrict__ b2, const float* __restrict__ W3,
    const float* __restrict__ b3, float* __restrict__ out) {
    const int b = blockIdx.x;
    const int tid = threadIdx.x;
    const int j = tid & 63;
    const int s = tid >> 6;

    __shared__ __align__(16) float sF[NT * IND];
    __shared__ __align__(16) float sSig[128];
    __shared__ float sA[IND], sB[IND], sC[IND * IND];
    __shared__ float sRel[IND];
    __shared__ __align__(16) float sPart[4 * 64];
    __shared__ __align__(16) float sH1[64];

    for (int idx = tid; idx < NT * IND; idx += 256)
        sF[idx] = features[b * (NT * IND) + idx];
    if (tid < 100) sC[tid] = 0.f;
    else if (tid < 110) sA[tid - 100] = 0.f;
    else if (tid < 120) sB[tid - 110] = 0.f;
    else if (tid >= 121 && tid < 128) sSig[tid] = 0.f;

    float vs[32], vb[32], vc[32];
#pragma unroll
    for (int mm = 0; mm < 32; ++mm) {
        int mp = 32 * s + mm;
        if (mp < 121) {
            vs[mm] = W1[(11 + mp) * 64 + j] + W1[(132 + mp) * 64 + j];
            vb[mm] = W1[(253 + mp) * 64 + j];
            vc[mm] = W1[(374 + mp) * 64 + j];
        } else { vs[mm] = 0.f; vb[mm] = 0.f; vc[mm] = 0.f; }
    }
    float ex[17];
#pragma unroll
    for (int q = 0; q < 17; ++q) ex[q] = 0.f;
    if (s == 1) {
#pragma unroll
        for (int q = 0; q < 11; ++q) ex[q] = W1[q * 64 + j];
    } else if (s == 2) {
#pragma unroll
        for (int q = 0; q < 10; ++q) ex[q] = W1[(512 + q) * 64 + j];
        ex[10] = b1[j];
    } else if (s == 3) {
#pragma unroll
        for (int q = 0; q < 17; ++q) ex[q] = W1[(495 + q) * 64 + j];
    }
    float w2p[16];
#pragma unroll
    for (int ii = 0; ii < 16; ++ii) w2p[ii] = W2[(16 * s + ii) * 64 + j];

    float w1l = 0.f, b2j = 0.f, w3j = 0.f, b3v = 0.f;
    if (s == 0) { w1l = W1[522 * 64 + j]; b2j = b2[j]; w3j = W3[j]; b3v = b3[0]; }
    float delta = 0.f;

    __syncthreads();

    for (int m = 0; m < NT; ++m) {
        if (m > 0) {
            if (tid < 100) {
                int i = tid / 10, c = tid % 10;
                float rp = sF[(m - 1) * 10 + i] - sF[i];
                float ic = sF[m * 10 + c] - sF[(m - 1) * 10 + c];
                sC[tid] += rp * ic;
            } else if (tid < 110) {
                int i = tid - 100;
                sA[i] += (float)(m - 1) * (sF[m * 10 + i] - sF[(m - 1) * 10 + i]);
            } else if (tid < 120) {
                int i = tid - 110;
                sB[i] += sF[(m - 1) * 10 + i] - sF[i];
            }
            __syncthreads();
            float inv_k = 1.0f / (float)m;
            if (tid == 0) sSig[0] = 0.5f * (float)(m - 1) * inv_k;
            else if (tid < 11) sSig[tid] = inv_k * sA[tid - 1];
            else if (tid < 121) {
                int i = tid / 11 - 1, c = tid % 11;
                sSig[tid] = (c == 0) ? inv_k * sB[i] : sC[i * 10 + (c - 1)];
            } else if (tid < 131) {
                int f = tid - 121;
                sRel[f] = sF[m * 10 + f] - sF[f];
            }
            __syncthreads();
        }
        float part = 0.f;
        if (m > 0) {
            float pa = 0.f, pb = 0.f, pc = 0.f;
#pragma unroll
            for (int q = 0; q < 8; ++q) {
                float4 sv = *(const float4*)&sSig[32 * s + 4 * q];
                pa = fmaf(sv.x, vs[4 * q + 0], pa);
                pb = fmaf(sv.x, vb[4 * q + 0], pb);
                pc = fmaf(sv.x, vc[4 * q + 0], pc);
                pa = fmaf(sv.y, vs[4 * q + 1], pa);
                pb = fmaf(sv.y, vb[4 * q + 1], pb);
                pc = fmaf(sv.y, vc[4 * q + 1], pc);
                pa = fmaf(sv.z, vs[4 * q + 2], pa);
                pb = fmaf(sv.z, vb[4 * q + 2], pb);
                pc = fmaf(sv.z, vc[4 * q + 2], pc);
                pa = fmaf(sv.w, vs[4 * q + 3], pa);
                pb = fmaf(sv.w, vb[4 * q + 3], pb);
                pc = fmaf(sv.w, vc[4 * q + 3], pc);
            }
            part = pa + sRel[0] * pb + sRel[1] * pc;
            if (s == 3) {
                float pd = 0.f;
#pragma unroll
                for (int q = 0; q < 17; ++q) pd = fmaf(sSig[q], ex[q], pd);
                part = fmaf(sRel[2], pd, part);
            }
            if (s == 1) {
                part += ex[0];
#pragma unroll
                for (int i = 0; i < 10; ++i) part = fmaf(sRel[i], ex[1 + i], part);
            }
        }
        if (s == 2) {
            float pf = ex[10];
#pragma unroll
            for (int f = 0; f < 10; ++f) pf = fmaf(sF[m * 10 + f], ex[f], pf);
            part += pf;
        }
        sPart[s * 64 + j] = part;
        __syncthreads();
        if (s == 0) {
            float x = sPart[j] + sPart[64 + j] + sPart[128 + j] + sPart[192 + j];
            sH1[j] = fmaxf(fmaf(delta, w1l, x), 0.f);
        }
        __syncthreads();
        {
            float hp = 0.f;
#pragma unroll
            for (int q = 0; q < 4; ++q) {
                float4 hv = *(const float4*)&sH1[16 * s + 4 * q];
                hp = fmaf(hv.x, w2p[4 * q + 0], hp);
                hp = fmaf(hv.y, w2p[4 * q + 1], hp);
                hp = fmaf(hv.z, w2p[4 * q + 2], hp);
                hp = fmaf(hv.w, w2p[4 * q + 3], hp);
            }
            sPart[s * 64 + j] = hp;
        }
        __syncthreads();
        if (s == 0) {
            float x2 = sPart[j] + sPart[64 + j] + sPart[128 + j] + sPart[192 + j] + b2j;
            float h2 = fmaxf(x2, 0.f);
            float dv = h2 * w3j;
#pragma unroll
            for (int off = 32; off > 0; off >>= 1) dv += __shfl_xor(dv, off, 64);
            delta = dv + b3v;
            if (j == 0) out[b * NT + m] = delta;
        }
        __syncthreads();
    }
}

extern "C" void kernel_launch(void* const* d_in, const int* in_sizes, int n_in,
                              void* d_out, int out_size, void* d_ws, size_t ws_size,
                              hipStream_t stream) {
    const float* features = (const float*)d_in[0];
    const float* W1 = (const float*)d_in[1];
    const float* b1 = (const float*)d_in[2];
    const float* W2 = (const float*)d_in[3];
    const float* b2 = (const float*)d_in[4];
    const float* W3 = (const float*)d_in[5];
    const float* b3 = (const float*)d_in[6];
    float* out = (float*)d_out;

    const size_t wr_pad   = 103936;                                 // 256B-aligned
    const size_t pre_bytes = (size_t)NB * NT * HID * sizeof(float); // 64 MiB
    if (ws_size >= wr_pad + pre_bytes) {
        float* Wr = (float*)d_ws;
        float* pre1 = (float*)((char*)d_ws + wr_pad);
        pack_kernel<<<(64 * WPJ + 255) / 256, 256, 0, stream>>>(W1, b1, Wr);
        presig_kernel<<<NB, NT, 0, stream>>>(features, Wr, pre1);
        scan_kernel<<<NB, 64, 0, stream>>>(pre1, W1, W2, b2, W3, b3, out);
    } else {
        logsig_hedge_fallback<<<NB, NT, 0, stream>>>(features, W1, b1, W2, b2, W3, b3, out);
    }
}